// Round 18
// baseline (1178.349 us; speedup 1.0000x reference)
//
#include <hip/hip_runtime.h>
#include <hip/hip_bf16.h>
#include <cstdint>

#define T_TOK 8192
#define DM 1024
#define NE 8
#define DFF 4096

#define PERX_UP 144   // 16 ct * up-to-9 gy per XCD (256-row tiles)
#define PERX_DN 72    // 4 ct * up-to-9 gy * 2 kh per XCD
#define GEMM_UP_BLOCKS (8 * PERX_UP)

// fused-pre block ranges
#define CVTX_BLOCKS 4096
#define CVTW_BLOCKS 16384
#define ROUT_BLOCKS 128   // 64 tokens per block, block-aggregated atomics

typedef __attribute__((ext_vector_type(8))) short bf16x8;
typedef __attribute__((ext_vector_type(4))) float f32x4;

__device__ __forceinline__ unsigned short f2bf(float f) {
  unsigned int b = __float_as_uint(f);
  b += 0x7FFFu + ((b >> 16) & 1u);
  return (unsigned short)(b >> 16);
}

__device__ __forceinline__ float gelu_exact(float v) {
  return 0.5f * v * (1.0f + erff(v * 0.70710678118654752440f));
}

__device__ __forceinline__ void cvt8(const float* __restrict__ src, unsigned short* __restrict__ dst,
                                     size_t i) {
  const f32x4* p = (const f32x4*)src;
  f32x4 a = p[2 * i];
  f32x4 b = p[2 * i + 1];
  union { bf16x8 v; unsigned short u[8]; } o;
  o.u[0] = f2bf(a.x); o.u[1] = f2bf(a.y); o.u[2] = f2bf(a.z); o.u[3] = f2bf(a.w);
  o.u[4] = f2bf(b.x); o.u[5] = f2bf(b.y); o.u[6] = f2bf(b.z); o.u[7] = f2bf(b.w);
  ((bf16x8*)dst)[i] = o.v;
}

// ---- standalone cvt (fallback path) ----
__global__ void cvt_kernel(const float* __restrict__ x, unsigned short* __restrict__ xb) {
  cvt8(x, xb, (size_t)blockIdx.x * blockDim.x + threadIdx.x);
}

// ---- fused: cvt_x | cvt_up | router (block-aggregated atomics) ----
__global__ void fused_pre_kernel(const float* __restrict__ x, unsigned short* __restrict__ xb,
                                 const float* __restrict__ up, unsigned short* __restrict__ upb,
                                 const float* __restrict__ rw, const float* __restrict__ rb,
                                 int* __restrict__ counts_pad, int* __restrict__ tlist,
                                 float* __restrict__ wlist) {
  const int bid = blockIdx.x;
  if (bid < CVTX_BLOCKS) {
    cvt8(x, xb, (size_t)bid * 256 + threadIdx.x);
    return;
  }
  if (bid < CVTX_BLOCKS + CVTW_BLOCKS) {
    cvt8(up, upb, (size_t)(bid - CVTX_BLOCKS) * 256 + threadIdx.x);
    return;
  }
  const int rblk = bid - CVTX_BLOCKS - CVTW_BLOCKS;
  __shared__ int hcnt[NE], hbase[NE];
  __shared__ int tE1[64], tE2[64], tR1[64], tR2[64];
  __shared__ float tW1[64], tW2[64];
  if (threadIdx.x < NE) hcnt[threadIdx.x] = 0;
  __syncthreads();
  const int wv = threadIdx.x >> 6, lane = threadIdx.x & 63;
#pragma unroll 1
  for (int it = 0; it < 16; ++it) {
    const int lt = wv * 16 + it;
    const int t = rblk * 64 + lt;
    const float* xr = x + (size_t)t * DM;
    float acc[NE];
#pragma unroll
    for (int e = 0; e < NE; ++e) acc[e] = 0.0f;
#pragma unroll
    for (int i = 0; i < 16; ++i) {
      int d = lane + i * 64;
      float xv = xr[d];
      const float* wr = rw + (size_t)d * NE;
#pragma unroll
      for (int e = 0; e < NE; ++e) acc[e] = fmaf(xv, wr[e], acc[e]);
    }
#pragma unroll
    for (int off = 32; off; off >>= 1) {
#pragma unroll
      for (int e = 0; e < NE; ++e) acc[e] += __shfl_xor(acc[e], off);
    }
    if (lane == 0) {
      float m = -1e30f;
#pragma unroll
      for (int e = 0; e < NE; ++e) { acc[e] += rb[e]; m = fmaxf(m, acc[e]); }
      float p[NE]; float s = 0.0f;
#pragma unroll
      for (int e = 0; e < NE; ++e) { p[e] = expf(acc[e] - m); s += p[e]; }
      int e1 = 0; float p1 = p[0];
#pragma unroll
      for (int e = 1; e < NE; ++e) if (p[e] > p1) { p1 = p[e]; e1 = e; }
      int e2 = -1; float p2 = -1e30f;
#pragma unroll
      for (int e = 0; e < NE; ++e) if (e != e1 && p[e] > p2) { p2 = p[e]; e2 = e; }
      float inv = 1.0f / s;
      int r1 = atomicAdd(&hcnt[e1], 1);
      int r2 = atomicAdd(&hcnt[e2], 1);
      tE1[lt] = e1; tR1[lt] = r1; tW1[lt] = p1 * inv;
      tE2[lt] = e2; tR2[lt] = r2; tW2[lt] = p2 * inv;
    }
  }
  __syncthreads();
  if (threadIdx.x < NE)
    hbase[threadIdx.x] = atomicAdd(&counts_pad[threadIdx.x * 16], hcnt[threadIdx.x]);
  __syncthreads();
  if (threadIdx.x < 64) {
    int lt = threadIdx.x;
    int t = rblk * 64 + lt;
    int e = tE1[lt]; int pos = hbase[e] + tR1[lt];
    tlist[e * T_TOK + pos] = t; wlist[e * T_TOK + pos] = tW1[lt];
    e = tE2[lt]; pos = hbase[e] + tR2[lt];
    tlist[e * T_TOK + pos] = t; wlist[e * T_TOK + pos] = tW2[lt];
  }
}

// ---- prefix + per-XCD worklists (256-row tiles); compacts padded counts ----
// pack: e<<24 | rt<<16 | kh<<8 | ct ; -1 = no work
__global__ void prefix_kernel(const int* __restrict__ counts_pad, int* __restrict__ cntc,
                              int* __restrict__ offs,
                              int* __restrict__ wl_up, int* __restrict__ wl_dn) {
  __shared__ int te[80], tr[80], sn;
  if (threadIdx.x == 0) {
    int s = 0, n = 0;
    for (int e = 0; e < NE; ++e) {
      int c = counts_pad[e * 16];
      cntc[e] = c;
      offs[e] = s; s += c;
      int ntile = (c + 255) / 256;
      for (int r = 0; r < ntile; ++r) { te[n] = e; tr[n] = r; ++n; }
    }
    sn = n;
  }
  __syncthreads();
  const int n = sn;
  for (int idx = threadIdx.x; idx < 8 * PERX_UP; idx += blockDim.x) {
    int k = idx / PERX_UP, i = idx % PERX_UP;
    int g0 = (n * k) / 8, g1 = (n * (k + 1)) / 8, gc = g1 - g0;
    int v = -1;
    if (gc > 0 && i < 16 * gc) {          // ct-outer (16), g-inner
      int ct = i / gc, g = g0 + i % gc;
      v = (te[g] << 24) | (tr[g] << 16) | ct;
    }
    wl_up[idx] = v;
  }
  for (int idx = threadIdx.x; idx < 8 * PERX_DN; idx += blockDim.x) {
    int k = idx / PERX_DN, i = idx % PERX_DN;
    int g0 = (n * k) / 8, g1 = (n * (k + 1)) / 8, gc = g1 - g0;
    int v = -1;
    if (gc > 0 && i < 8 * gc) {           // kh-outer, ct-mid (4), g-inner
      int kh = i / (4 * gc);
      int rem = i % (4 * gc);
      int ct = rem / gc, g = g0 + rem % gc;
      v = (te[g] << 24) | (tr[g] << 16) | (kh << 8) | ct;
    }
    wl_dn[idx] = v;
  }
}

#define GL2LDS16(g, l) \
  __builtin_amdgcn_global_load_lds((const __attribute__((address_space(1))) unsigned int*)(g), \
                                   (__attribute__((address_space(3))) unsigned int*)(l), 16, 0, 0)

#define VMCNT4   asm volatile("s_waitcnt vmcnt(4)" ::: "memory")
#define VMCNT0   asm volatile("s_waitcnt vmcnt(0)" ::: "memory")
#define LGKM0    asm volatile("s_waitcnt lgkmcnt(0)" ::: "memory")
#define BARRIER() do { asm volatile("" ::: "memory"); __builtin_amdgcn_s_barrier(); asm volatile("" ::: "memory"); } while (0)

// 512 threads stage one 256x32 operand per 2 issues (rows tid>>2, +128); 4 issues/step
// LDS: sA[2] at bi*8192 shorts (16 KB each), sB[2] at 16384 + bi*8192 shorts
#define STAGE(bi, t) do { \
  const int k_ = (t) * 32; \
  GL2LDS16(asrc0 + k_, smem + (bi) * 8192 + tid * 8); \
  GL2LDS16(asrc1 + k_, smem + (bi) * 8192 + 4096 + tid * 8); \
  GL2LDS16(bsrc0 + k_, smem + 16384 + (bi) * 8192 + tid * 8); \
  GL2LDS16(bsrc1 + k_, smem + 16384 + (bi) * 8192 + 4096 + tid * 8); \
} while (0)

// per-wave 128x64 output: 8 A-frags + 4 B-frags, 32 MFMA
#define COMPUTE(bi) do { \
  const unsigned short* sA_ = smem + (bi) * 8192; \
  const unsigned short* sB_ = smem + 16384 + (bi) * 8192; \
  bf16x8 af_[8], bf_[4]; \
  _Pragma("unroll") \
  for (int m_ = 0; m_ < 8; ++m_) af_[m_] = *(const bf16x8*)(sA_ + (wr + m_ * 16 + lr) * 32 + kx); \
  _Pragma("unroll") \
  for (int n_ = 0; n_ < 4; ++n_) bf_[n_] = *(const bf16x8*)(sB_ + (wc + n_ * 16 + lr) * 32 + kx); \
  _Pragma("unroll") \
  for (int m_ = 0; m_ < 8; ++m_) \
    _Pragma("unroll") \
    for (int n_ = 0; n_ < 4; ++n_) \
      acc[m_][n_] = __builtin_amdgcn_mfma_f32_16x16x32_bf16(af_[m_], bf_[n_], acc[m_][n_], 0, 0, 0); \
} while (0)

// depth-2 pipelined K-loop (R12-proven schedule)
#define KLOOP(NT) do { \
  STAGE(0, 0); \
  STAGE(1, 1); \
  for (int t = 0; t < (NT); ++t) { \
    const int b_ = t & 1; \
    if (t + 1 < (NT)) { VMCNT4; } else { VMCNT0; } \
    BARRIER(); \
    COMPUTE(b_); \
    if (t + 2 < (NT)) { \
      LGKM0; \
      BARRIER(); \
      STAGE(b_, t + 2); \
    } \
  } \
} while (0)

// ---- GEMM1: h = gelu(x[tok] @ up[e]^T), 256x256/BK=32, 8 waves; trailing blocks cvt dn ----
__global__ __launch_bounds__(512, 2) void gemm_up_kernel(
    const unsigned short* __restrict__ xb, const unsigned short* __restrict__ wb,
    const int* __restrict__ cntc, const int* __restrict__ offs,
    const int* __restrict__ wl, const int* __restrict__ tlist,
    unsigned short* __restrict__ h,
    const float* __restrict__ dn_f32, unsigned short* __restrict__ dn_bf16) {
  if ((int)blockIdx.x >= GEMM_UP_BLOCKS) {
    // FIX (R17 crash): second-half offset is CVTW_BLOCKS/4 * 512 (not /2),
    // so 4096 blocks x 512 thr x 2 calls cover exactly [0, 4194304) cvt8 units.
    size_t base = (size_t)(blockIdx.x - GEMM_UP_BLOCKS) * 512 + threadIdx.x;
    cvt8(dn_f32, dn_bf16, base);
    cvt8(dn_f32, dn_bf16, base + (size_t)(CVTW_BLOCKS / 4) * 512);
    return;
  }
  const int xcd = blockIdx.x & 7, slot = blockIdx.x >> 3;
  const int item = wl[xcd * PERX_UP + slot];
  if (item < 0) return;
  const int e = (item >> 24) & 7, rt = (item >> 16) & 0xFF, ct = item & 0xFF;
  const int cnt = cntc[e];

  __shared__ unsigned short smem[32768];   // 64 KB: sA[2]x16KB + sB[2]x16KB; sH reuses all

  const int tid = threadIdx.x;
  const int wid = tid >> 6, ln = tid & 63;
  const int swz = (tid & 3) ^ ((tid >> 3) & 3);

  int r0 = rt * 256 + (tid >> 2), r1 = r0 + 128;
  const int tok0 = tlist[e * T_TOK + (r0 < cnt ? r0 : cnt - 1)];
  const int tok1 = tlist[e * T_TOK + (r1 < cnt ? r1 : cnt - 1)];
  const unsigned short* asrc0 = xb + (size_t)tok0 * DM + swz * 8;
  const unsigned short* asrc1 = xb + (size_t)tok1 * DM + swz * 8;

  const unsigned short* bsrc0 =
      wb + (size_t)e * DFF * DM + (size_t)(ct * 256 + (tid >> 2)) * DM + swz * 8;
  const unsigned short* bsrc1 = bsrc0 + (size_t)128 * DM;

  const int wr = (wid >> 2) * 128, wc = (wid & 3) * 64;
  const int lr = ln & 15, g4 = ln >> 4;
  const int kx = ((g4 ^ ((lr >> 1) & 3))) * 8;

  f32x4 acc[8][4] = {};

  KLOOP(DM / 32);   // 32 steps

  BARRIER();        // all waves done with sA/sB before reuse as sH

  // 2-half bounce epilogue: sH = [128][256] (64 KB)
  unsigned short* sH = smem;
  const size_t hbase = (size_t)offs[e];
#pragma unroll 1
  for (int half = 0; half < 2; ++half) {
    if ((wid >> 2) == half) {
#pragma unroll
      for (int m = 0; m < 8; ++m) {
        int rloc = m * 16 + g4 * 4;   // local row within half (wr - half*128 = 0)
#pragma unroll
        for (int j = 0; j < 4; ++j) {
          int row = rloc + j;
#pragma unroll
          for (int n = 0; n < 4; ++n) {
            int col = wc + n * 16 + lr;
            int sl = ((col >> 3) ^ (row & 7)) * 8 + (col & 7);
            sH[row * 256 + sl] = f2bf(gelu_exact(acc[m][n][j]));
          }
        }
      }
    }
    __syncthreads();
#pragma unroll
    for (int it = 0; it < 8; ++it) {
      int idx = it * 512 + tid;
      int row = idx >> 5, c8 = idx & 31;
      int grow = rt * 256 + half * 128 + row;
      if (grow < cnt) {
        unsigned short* hp = h + (hbase + grow) * (size_t)DFF + ct * 256 + c8 * 8;
        *(bf16x8*)hp = *(const bf16x8*)&sH[row * 256 + (c8 ^ (row & 7)) * 8];
      }
    }
    __syncthreads();
  }
}

// ---- GEMM2: out[tok] += w * (h @ down[e]^T), 256x256/BK=32, K-split-2, 8 waves ----
__global__ __launch_bounds__(512, 2) void gemm_down_kernel(
    const unsigned short* __restrict__ h, const unsigned short* __restrict__ wb,
    const int* __restrict__ cntc, const int* __restrict__ offs,
    const int* __restrict__ wl, const int* __restrict__ tlist,
    const float* __restrict__ wlist, float* __restrict__ out) {
  const int xcd = blockIdx.x & 7, slot = blockIdx.x >> 3;
  const int item = wl[xcd * PERX_DN + slot];
  if (item < 0) return;
  const int e = (item >> 24) & 7, rt = (item >> 16) & 0xFF;
  const int kh = (item >> 8) & 1, ct = item & 0xFF;
  const int cnt = cntc[e];

  __shared__ unsigned short smem[32768];   // 64 KB

  const int tid = threadIdx.x;
  const int wid = tid >> 6, ln = tid & 63;
  const int swz = (tid & 3) ^ ((tid >> 3) & 3);
  const size_t hbase = (size_t)offs[e];
  const int kbase = kh * (DFF / 2);

  int r0 = rt * 256 + (tid >> 2), r1 = r0 + 128;
  const unsigned short* asrc0 =
      h + (hbase + (r0 < cnt ? r0 : cnt - 1)) * (size_t)DFF + kbase + swz * 8;
  const unsigned short* asrc1 =
      h + (hbase + (r1 < cnt ? r1 : cnt - 1)) * (size_t)DFF + kbase + swz * 8;

  const unsigned short* bsrc0 =
      wb + (size_t)e * DM * DFF + (size_t)(ct * 256 + (tid >> 2)) * DFF + kbase + swz * 8;
  const unsigned short* bsrc1 = bsrc0 + (size_t)128 * DFF;

  const int wr = (wid >> 2) * 128, wc = (wid & 3) * 64;
  const int lr = ln & 15, g4 = ln >> 4;
  const int kx = ((g4 ^ ((lr >> 1) & 3))) * 8;

  f32x4 acc[8][4] = {};

  KLOOP(DFF / 2 / 32);   // 64 steps

#pragma unroll
  for (int m = 0; m < 8; ++m) {
    int rloc = wr + m * 16 + g4 * 4;
#pragma unroll
    for (int j = 0; j < 4; ++j) {
      int row = rt * 256 + rloc + j;
      if (row < cnt) {
        int tok = tlist[e * T_TOK + row];
        float w = wlist[e * T_TOK + row];
        float* op = out + (size_t)tok * DM + ct * 256 + wc + lr;
#pragma unroll
        for (int n = 0; n < 4; ++n) atomicAdd(op + n * 16, w * acc[m][n][j]);
      }
    }
  }
}

extern "C" void kernel_launch(void* const* d_in, const int* in_sizes, int n_in,
                              void* d_out, int out_size, void* d_ws, size_t ws_size,
                              hipStream_t stream) {
  const float* x  = (const float*)d_in[0];
  const float* rw = (const float*)d_in[1];
  const float* rb = (const float*)d_in[2];
  const float* up = (const float*)d_in[3];
  const float* dn = (const float*)d_in[4];
  float* out = (float*)d_out;
  char* ws = (char*)d_ws;

  int*   counts_pad = (int*)(ws + 0);                       // 8 counters x 64B
  int*   cntc   = (int*)(ws + 1024);
  int*   offs   = (int*)(ws + 2048);
  int*   wl_up  = (int*)(ws + 4096);                        // 8*144 ints
  int*   wl_dn  = (int*)(ws + 24576);                       // 8*72 ints
  int*   tlist  = (int*)(ws + 65536);                       // 256 KB
  float* wlist  = (float*)(ws + 65536 + 262144);            // 256 KB
  unsigned short* xb    = (unsigned short*)(ws + 589824);   // 16 MB
  unsigned short* h     = (unsigned short*)(ws + 17367040); // 128 MB
  unsigned short* wbufA = (unsigned short*)(ws + 151584768);// 64 MB (up weights)
  unsigned short* wbufB = (unsigned short*)(ws + 218693632);// 64 MB (dn weights, big-ws only)
  const bool big_ws = (ws_size >= (size_t)218693632 + 67108864);

  hipMemsetAsync(counts_pad, 0, 512, stream);
  hipMemsetAsync(d_out, 0, (size_t)T_TOK * DM * sizeof(float), stream);

  fused_pre_kernel<<<dim3(CVTX_BLOCKS + CVTW_BLOCKS + ROUT_BLOCKS), 256, 0, stream>>>(
      x, xb, up, wbufA, rw, rb, counts_pad, tlist, wlist);
  prefix_kernel<<<dim3(1), 256, 0, stream>>>(counts_pad, cntc, offs, wl_up, wl_dn);

  if (big_ws) {
    // gemm_up (512 thr) + trailing cvt-dn blocks (each cvt block does 2x512x8 elems)
    gemm_up_kernel<<<dim3(GEMM_UP_BLOCKS + CVTW_BLOCKS / 4), 512, 0, stream>>>(
        xb, wbufA, cntc, offs, wl_up, tlist, h, dn, wbufB);
    gemm_down_kernel<<<dim3(8 * PERX_DN), 512, 0, stream>>>(
        h, wbufB, cntc, offs, wl_dn, tlist, wlist, out);
  } else {
    gemm_up_kernel<<<dim3(GEMM_UP_BLOCKS), 512, 0, stream>>>(
        xb, wbufA, cntc, offs, wl_up, tlist, h, dn, wbufA);
    cvt_kernel<<<dim3(CVTW_BLOCKS), 256, 0, stream>>>(dn, (unsigned short*)wbufA);
    gemm_down_kernel<<<dim3(8 * PERX_DN), 512, 0, stream>>>(
        h, wbufA, cntc, offs, wl_dn, tlist, wlist, out);
  }
}

// Round 19
// 670.665 us; speedup vs baseline: 1.7570x; 1.7570x over previous
//
#include <hip/hip_runtime.h>
#include <hip/hip_bf16.h>
#include <cstdint>

#define T_TOK 8192
#define DM 1024
#define NE 8
#define DFF 4096

#define PERX_UP 576   // 32 ct * up-to-18 gy per XCD
#define PERX_DN 288   // 8 ct * up-to-18 gy * 2 kh per XCD
#define GEMM_UP_BLOCKS (8 * PERX_UP)

// fused-pre block ranges
#define CVTX_BLOCKS 4096
#define CVTW_BLOCKS 16384
#define ROUT_BLOCKS 128   // 64 tokens per block, block-aggregated atomics

typedef __attribute__((ext_vector_type(8))) short bf16x8;
typedef __attribute__((ext_vector_type(4))) float f32x4;

__device__ __forceinline__ unsigned short f2bf(float f) {
  unsigned int b = __float_as_uint(f);
  b += 0x7FFFu + ((b >> 16) & 1u);
  return (unsigned short)(b >> 16);
}

__device__ __forceinline__ float gelu_exact(float v) {
  return 0.5f * v * (1.0f + erff(v * 0.70710678118654752440f));
}

__device__ __forceinline__ void cvt8(const float* __restrict__ src, unsigned short* __restrict__ dst,
                                     size_t i) {
  const f32x4* p = (const f32x4*)src;
  f32x4 a = p[2 * i];
  f32x4 b = p[2 * i + 1];
  union { bf16x8 v; unsigned short u[8]; } o;
  o.u[0] = f2bf(a.x); o.u[1] = f2bf(a.y); o.u[2] = f2bf(a.z); o.u[3] = f2bf(a.w);
  o.u[4] = f2bf(b.x); o.u[5] = f2bf(b.y); o.u[6] = f2bf(b.z); o.u[7] = f2bf(b.w);
  ((bf16x8*)dst)[i] = o.v;
}

// ---- standalone cvt (fallback path) ----
__global__ void cvt_kernel(const float* __restrict__ x, unsigned short* __restrict__ xb) {
  cvt8(x, xb, (size_t)blockIdx.x * blockDim.x + threadIdx.x);
}

// ---- fused: cvt_x | cvt_up | router (block-aggregated atomics) ----
__global__ void fused_pre_kernel(const float* __restrict__ x, unsigned short* __restrict__ xb,
                                 const float* __restrict__ up, unsigned short* __restrict__ upb,
                                 const float* __restrict__ rw, const float* __restrict__ rb,
                                 int* __restrict__ counts_pad, int* __restrict__ tlist,
                                 float* __restrict__ wlist) {
  const int bid = blockIdx.x;
  if (bid < CVTX_BLOCKS) {
    cvt8(x, xb, (size_t)bid * 256 + threadIdx.x);
    return;
  }
  if (bid < CVTX_BLOCKS + CVTW_BLOCKS) {
    cvt8(up, upb, (size_t)(bid - CVTX_BLOCKS) * 256 + threadIdx.x);
    return;
  }
  const int rblk = bid - CVTX_BLOCKS - CVTW_BLOCKS;
  __shared__ int hcnt[NE], hbase[NE];
  __shared__ int tE1[64], tE2[64], tR1[64], tR2[64];
  __shared__ float tW1[64], tW2[64];
  if (threadIdx.x < NE) hcnt[threadIdx.x] = 0;
  __syncthreads();
  const int wv = threadIdx.x >> 6, lane = threadIdx.x & 63;
#pragma unroll 1
  for (int it = 0; it < 16; ++it) {
    const int lt = wv * 16 + it;
    const int t = rblk * 64 + lt;
    const float* xr = x + (size_t)t * DM;
    float acc[NE];
#pragma unroll
    for (int e = 0; e < NE; ++e) acc[e] = 0.0f;
#pragma unroll
    for (int i = 0; i < 16; ++i) {
      int d = lane + i * 64;
      float xv = xr[d];
      const float* wr = rw + (size_t)d * NE;
#pragma unroll
      for (int e = 0; e < NE; ++e) acc[e] = fmaf(xv, wr[e], acc[e]);
    }
#pragma unroll
    for (int off = 32; off; off >>= 1) {
#pragma unroll
      for (int e = 0; e < NE; ++e) acc[e] += __shfl_xor(acc[e], off);
    }
    if (lane == 0) {
      float m = -1e30f;
#pragma unroll
      for (int e = 0; e < NE; ++e) { acc[e] += rb[e]; m = fmaxf(m, acc[e]); }
      float p[NE]; float s = 0.0f;
#pragma unroll
      for (int e = 0; e < NE; ++e) { p[e] = expf(acc[e] - m); s += p[e]; }
      int e1 = 0; float p1 = p[0];
#pragma unroll
      for (int e = 1; e < NE; ++e) if (p[e] > p1) { p1 = p[e]; e1 = e; }
      int e2 = -1; float p2 = -1e30f;
#pragma unroll
      for (int e = 0; e < NE; ++e) if (e != e1 && p[e] > p2) { p2 = p[e]; e2 = e; }
      float inv = 1.0f / s;
      int r1 = atomicAdd(&hcnt[e1], 1);
      int r2 = atomicAdd(&hcnt[e2], 1);
      tE1[lt] = e1; tR1[lt] = r1; tW1[lt] = p1 * inv;
      tE2[lt] = e2; tR2[lt] = r2; tW2[lt] = p2 * inv;
    }
  }
  __syncthreads();
  if (threadIdx.x < NE)
    hbase[threadIdx.x] = atomicAdd(&counts_pad[threadIdx.x * 16], hcnt[threadIdx.x]);
  __syncthreads();
  if (threadIdx.x < 64) {
    int lt = threadIdx.x;
    int t = rblk * 64 + lt;
    int e = tE1[lt]; int pos = hbase[e] + tR1[lt];
    tlist[e * T_TOK + pos] = t; wlist[e * T_TOK + pos] = tW1[lt];
    e = tE2[lt]; pos = hbase[e] + tR2[lt];
    tlist[e * T_TOK + pos] = t; wlist[e * T_TOK + pos] = tW2[lt];
  }
}

// ---- prefix + per-XCD worklists (parallel fill); compacts padded counts ----
// pack: e<<24 | rt<<16 | kh<<8 | ct ; -1 = no work
// wl_up uses 8g x 8ct super-tiles to bound the live L2 panel window.
__global__ void prefix_kernel(const int* __restrict__ counts_pad, int* __restrict__ cntc,
                              int* __restrict__ offs,
                              int* __restrict__ wl_up, int* __restrict__ wl_dn) {
  __shared__ int te[144], tr[144], sn;
  if (threadIdx.x == 0) {
    int s = 0, n = 0;
    for (int e = 0; e < NE; ++e) {
      int c = counts_pad[e * 16];
      cntc[e] = c;
      offs[e] = s; s += c;
      int ntile = (c + 127) / 128;
      for (int r = 0; r < ntile; ++r) { te[n] = e; tr[n] = r; ++n; }
    }
    sn = n;
  }
  __syncthreads();
  const int n = sn;
  for (int idx = threadIdx.x; idx < 8 * PERX_UP; idx += blockDim.x) {
    int k = idx / PERX_UP, i = idx % PERX_UP;
    int g0 = (n * k) / 8, g1 = (n * (k + 1)) / 8, gc = g1 - g0;
    int v = -1;
    if (gc > 0 && i < 32 * gc) {
      // super-tiled: gsb blocks of up to 8 g-rows; within each, 4 csb runs of 8 ct
      int rem = i, gsb = 0, gs = (gc < 8 ? gc : 8);
      while (rem >= 32 * gs) {
        rem -= 32 * gs; ++gsb;
        int left = gc - gsb * 8; gs = (left < 8 ? left : 8);
      }
      int csb = rem / (8 * gs);
      int r2 = rem % (8 * gs);
      int gi = r2 / 8, ci = r2 & 7;
      int ct = csb * 8 + ci;
      int g = g0 + gsb * 8 + gi;
      v = (te[g] << 24) | (tr[g] << 16) | ct;
    }
    wl_up[idx] = v;
  }
  for (int idx = threadIdx.x; idx < 8 * PERX_DN; idx += blockDim.x) {
    int k = idx / PERX_DN, i = idx % PERX_DN;
    int g0 = (n * k) / 8, g1 = (n * (k + 1)) / 8, gc = g1 - g0;
    int v = -1;
    if (gc > 0 && i < 16 * gc) {          // kh-outer, ct-mid, g-inner
      int kh = i / (8 * gc);
      int rem = i % (8 * gc);
      int ct = rem / gc, g = g0 + rem % gc;
      v = (te[g] << 24) | (tr[g] << 16) | (kh << 8) | ct;
    }
    wl_dn[idx] = v;
  }
}

#define GL2LDS16(g, l) \
  __builtin_amdgcn_global_load_lds((const __attribute__((address_space(1))) unsigned int*)(g), \
                                   (__attribute__((address_space(3))) unsigned int*)(l), 16, 0, 0)

#define VMCNT4   asm volatile("s_waitcnt vmcnt(4)" ::: "memory")
#define VMCNT0   asm volatile("s_waitcnt vmcnt(0)" ::: "memory")
#define LGKM0    asm volatile("s_waitcnt lgkmcnt(0)" ::: "memory")
#define BARRIER() do { asm volatile("" ::: "memory"); __builtin_amdgcn_s_barrier(); asm volatile("" ::: "memory"); } while (0)

// per-wave staging: 4 gl2lds (2 A + 2 B) into buffer bi; tile t covers k0 = t*32
#define STAGE(bi, t) do { \
  const int k_ = (t) * 32; \
  GL2LDS16(asrc0 + k_, smem + (bi) * 4096 + wv * 512); \
  GL2LDS16(asrc1 + k_, smem + (bi) * 4096 + wv * 512 + 2048); \
  GL2LDS16(bsrc0 + k_, smem + 8192 + (bi) * 4096 + wv * 512); \
  GL2LDS16(bsrc1 + k_, smem + 8192 + (bi) * 4096 + wv * 512 + 2048); \
} while (0)

// swizzled reads + 16 MFMA on buffer bi
#define COMPUTE(bi) do { \
  const unsigned short* sA_ = smem + (bi) * 4096; \
  const unsigned short* sB_ = smem + 8192 + (bi) * 4096; \
  bf16x8 af_[4], bf_[4]; \
  _Pragma("unroll") \
  for (int m_ = 0; m_ < 4; ++m_) af_[m_] = *(const bf16x8*)(sA_ + (wr + m_ * 16 + lr) * 32 + kx); \
  _Pragma("unroll") \
  for (int n_ = 0; n_ < 4; ++n_) bf_[n_] = *(const bf16x8*)(sB_ + (wc + n_ * 16 + lr) * 32 + kx); \
  _Pragma("unroll") \
  for (int m_ = 0; m_ < 4; ++m_) \
    _Pragma("unroll") \
    for (int n_ = 0; n_ < 4; ++n_) \
      acc[m_][n_] = __builtin_amdgcn_mfma_f32_16x16x32_bf16(af_[m_], bf_[n_], acc[m_][n_], 0, 0, 0); \
} while (0)

// depth-2 pipelined K-loop: tile t's loads issued 2 steps ahead -> no exposed latency
#define KLOOP(NT) do { \
  STAGE(0, 0); \
  STAGE(1, 1); \
  for (int t = 0; t < (NT); ++t) { \
    const int b_ = t & 1; \
    if (t + 1 < (NT)) { VMCNT4; } else { VMCNT0; } \
    BARRIER(); \
    COMPUTE(b_); \
    if (t + 2 < (NT)) { \
      LGKM0; \
      BARRIER(); \
      STAGE(b_, t + 2); \
    } \
  } \
} while (0)

// ---- GEMM1: h = gelu(x[tok] @ up[e]^T), 128x128/BK=32, depth-2; trailing blocks cvt dn ----
__global__ __launch_bounds__(256, 4) void gemm_up_kernel(
    const unsigned short* __restrict__ xb, const unsigned short* __restrict__ wb,
    const int* __restrict__ cntc, const int* __restrict__ offs,
    const int* __restrict__ wl, const int* __restrict__ tlist,
    unsigned short* __restrict__ h,
    const float* __restrict__ dn_f32, unsigned short* __restrict__ dn_bf16) {
  if ((int)blockIdx.x >= GEMM_UP_BLOCKS) {
    cvt8(dn_f32, dn_bf16, (size_t)(blockIdx.x - GEMM_UP_BLOCKS) * 256 + threadIdx.x);
    return;
  }
  const int xcd = blockIdx.x & 7, slot = blockIdx.x >> 3;
  const int item = wl[xcd * PERX_UP + slot];
  if (item < 0) return;
  const int e = (item >> 24) & 7, rt = (item >> 16) & 0xFF, ct = item & 0xFF;
  const int cnt = cntc[e];

  __shared__ unsigned short smem[16384];   // 32 KB: sA[2] + sB[2]; sH bounce reuses

  const int tid = threadIdx.x;
  const int wv = tid >> 6, ln = tid & 63;
  const int swz = (tid & 3) ^ ((tid >> 3) & 3);

  const int arow = wv * 16 + (ln >> 2);
  int r0 = rt * 128 + arow;
  int r1 = r0 + 64;
  const int tok0 = tlist[e * T_TOK + (r0 < cnt ? r0 : cnt - 1)];
  const int tok1 = tlist[e * T_TOK + (r1 < cnt ? r1 : cnt - 1)];
  const unsigned short* asrc0 = xb + (size_t)tok0 * DM + swz * 8;
  const unsigned short* asrc1 = xb + (size_t)tok1 * DM + swz * 8;

  const unsigned short* bsrc0 =
      wb + (size_t)e * DFF * DM + (size_t)(ct * 128 + arow) * DM + swz * 8;
  const unsigned short* bsrc1 = bsrc0 + (size_t)64 * DM;

  const int wr = (wv >> 1) * 64, wc = (wv & 1) * 64;
  const int lr = ln & 15;
  const int kx = (((ln >> 4) ^ ((lr >> 1) & 3))) * 8;

  f32x4 acc[4][4] = {};

  KLOOP(DM / 32);   // 32 steps

  BARRIER();        // all waves done with sA/sB before reuse as sH

  unsigned short* sH = smem;               // [128][128] = 32 KB
#pragma unroll
  for (int m = 0; m < 4; ++m) {
    int rloc = wr + m * 16 + (ln >> 4) * 4;
#pragma unroll
    for (int j = 0; j < 4; ++j) {
      int row = rloc + j;
#pragma unroll
      for (int n = 0; n < 4; ++n) {
        int col = wc + n * 16 + lr;
        int sl = ((col >> 3) ^ (row & 7)) * 8 + (col & 7);
        sH[row * 128 + sl] = f2bf(gelu_exact(acc[m][n][j]));
      }
    }
  }
  __syncthreads();
  const size_t hbase = (size_t)offs[e];
#pragma unroll
  for (int it = 0; it < 8; ++it) {
    int idx = it * 256 + tid;
    int row = idx >> 4, c8 = idx & 15;
    if (rt * 128 + row < cnt) {
      unsigned short* hp = h + (hbase + rt * 128 + row) * (size_t)DFF + ct * 128 + c8 * 8;
      *(bf16x8*)hp = *(const bf16x8*)&sH[row * 128 + (c8 ^ (row & 7)) * 8];
    }
  }
}

// ---- GEMM2: out[tok] += w * (h @ down[e]^T), 128x128/BK=32, K-split-2, depth-2 ----
__global__ __launch_bounds__(256, 4) void gemm_down_kernel(
    const unsigned short* __restrict__ h, const unsigned short* __restrict__ wb,
    const int* __restrict__ cntc, const int* __restrict__ offs,
    const int* __restrict__ wl, const int* __restrict__ tlist,
    const float* __restrict__ wlist, float* __restrict__ out) {
  const int xcd = blockIdx.x & 7, slot = blockIdx.x >> 3;
  const int item = wl[xcd * PERX_DN + slot];
  if (item < 0) return;
  const int e = (item >> 24) & 7, rt = (item >> 16) & 0xFF;
  const int kh = (item >> 8) & 1, ct = item & 0xFF;
  const int cnt = cntc[e];

  __shared__ unsigned short smem[16384];   // 32 KB

  const int tid = threadIdx.x;
  const int wv = tid >> 6, ln = tid & 63;
  const int swz = (tid & 3) ^ ((tid >> 3) & 3);
  const size_t hbase = (size_t)offs[e];
  const int kbase = kh * (DFF / 2);

  const int arow = wv * 16 + (ln >> 2);
  int r0 = rt * 128 + arow;
  int r1 = r0 + 64;
  const unsigned short* asrc0 =
      h + (hbase + (r0 < cnt ? r0 : cnt - 1)) * (size_t)DFF + kbase + swz * 8;
  const unsigned short* asrc1 =
      h + (hbase + (r1 < cnt ? r1 : cnt - 1)) * (size_t)DFF + kbase + swz * 8;

  const unsigned short* bsrc0 =
      wb + (size_t)e * DM * DFF + (size_t)(ct * 128 + arow) * DFF + kbase + swz * 8;
  const unsigned short* bsrc1 = bsrc0 + (size_t)64 * DFF;

  const int wr = (wv >> 1) * 64, wc = (wv & 1) * 64;
  const int lr = ln & 15;
  const int kx = (((ln >> 4) ^ ((lr >> 1) & 3))) * 8;

  f32x4 acc[4][4] = {};

  KLOOP(DFF / 2 / 32);   // 64 steps

#pragma unroll
  for (int m = 0; m < 4; ++m) {
    int rloc = wr + m * 16 + (ln >> 4) * 4;
#pragma unroll
    for (int j = 0; j < 4; ++j) {
      int row = rt * 128 + rloc + j;
      if (row < cnt) {
        int tok = tlist[e * T_TOK + row];
        float w = wlist[e * T_TOK + row];
        float* op = out + (size_t)tok * DM + ct * 128 + wc + lr;
#pragma unroll
        for (int n = 0; n < 4; ++n) atomicAdd(op + n * 16, w * acc[m][n][j]);
      }
    }
  }
}

extern "C" void kernel_launch(void* const* d_in, const int* in_sizes, int n_in,
                              void* d_out, int out_size, void* d_ws, size_t ws_size,
                              hipStream_t stream) {
  const float* x  = (const float*)d_in[0];
  const float* rw = (const float*)d_in[1];
  const float* rb = (const float*)d_in[2];
  const float* up = (const float*)d_in[3];
  const float* dn = (const float*)d_in[4];
  float* out = (float*)d_out;
  char* ws = (char*)d_ws;

  int*   counts_pad = (int*)(ws + 0);                       // 8 counters x 64B
  int*   cntc   = (int*)(ws + 1024);
  int*   offs   = (int*)(ws + 2048);
  int*   wl_up  = (int*)(ws + 4096);                        // 8*576 ints
  int*   wl_dn  = (int*)(ws + 24576);                       // 8*288 ints
  int*   tlist  = (int*)(ws + 65536);                       // 256 KB
  float* wlist  = (float*)(ws + 65536 + 262144);            // 256 KB
  unsigned short* xb    = (unsigned short*)(ws + 589824);   // 16 MB
  unsigned short* h     = (unsigned short*)(ws + 17367040); // 128 MB
  unsigned short* wbufA = (unsigned short*)(ws + 151584768);// 64 MB (up weights)
  unsigned short* wbufB = (unsigned short*)(ws + 218693632);// 64 MB (dn weights, big-ws only)
  const bool big_ws = (ws_size >= (size_t)218693632 + 67108864);

  hipMemsetAsync(counts_pad, 0, 512, stream);
  hipMemsetAsync(d_out, 0, (size_t)T_TOK * DM * sizeof(float), stream);

  fused_pre_kernel<<<dim3(CVTX_BLOCKS + CVTW_BLOCKS + ROUT_BLOCKS), 256, 0, stream>>>(
      x, xb, up, wbufA, rw, rb, counts_pad, tlist, wlist);
  prefix_kernel<<<dim3(1), 256, 0, stream>>>(counts_pad, cntc, offs, wl_up, wl_dn);

  if (big_ws) {
    // gemm_up (256 thr) + trailing cvt-dn blocks (overlapped); gemm_down reads wbufB
    gemm_up_kernel<<<dim3(GEMM_UP_BLOCKS + CVTW_BLOCKS), 256, 0, stream>>>(
        xb, wbufA, cntc, offs, wl_up, tlist, h, dn, wbufB);
    gemm_down_kernel<<<dim3(8 * PERX_DN), 256, 0, stream>>>(
        h, wbufB, cntc, offs, wl_dn, tlist, wlist, out);
  } else {
    gemm_up_kernel<<<dim3(GEMM_UP_BLOCKS), 256, 0, stream>>>(
        xb, wbufA, cntc, offs, wl_up, tlist, h, dn, wbufA);
    cvt_kernel<<<dim3(CVTW_BLOCKS), 256, 0, stream>>>(dn, (unsigned short*)wbufA);
    gemm_down_kernel<<<dim3(8 * PERX_DN), 256, 0, stream>>>(
        h, wbufA, cntc, offs, wl_dn, tlist, wlist, out);
  }
}

// Round 20
// 561.026 us; speedup vs baseline: 2.1003x; 1.1954x over previous
//
#include <hip/hip_runtime.h>
#include <hip/hip_bf16.h>
#include <cstdint>

#define T_TOK 8192
#define DM 1024
#define NE 8
#define DFF 4096

#define PERX_UP 576   // 32 ct * up-to-18 gy per XCD
#define PERX_DN 288   // 8 ct * up-to-18 gy * 2 kh per XCD
#define GEMM_UP_BLOCKS (8 * PERX_UP)

// fused-pre: router blocks first, then grid-stride cvt blocks
#define ROUT_BLOCKS 128            // 64 tokens per block, block-aggregated atomics
#define CVT_GS_BLOCKS 2048         // grid-stride cvt (G11)
#define CVT_GS_THREADS ((size_t)CVT_GS_BLOCKS * 256)
#define NXU  ((size_t)T_TOK * DM / 8)        // 1,048,576 cvt8 units
#define NWU  ((size_t)NE * DFF * DM / 8)     // 4,194,304 cvt8 units

typedef __attribute__((ext_vector_type(8))) short bf16x8;
typedef __attribute__((ext_vector_type(4))) float f32x4;

__device__ __forceinline__ unsigned short f2bf(float f) {
  unsigned int b = __float_as_uint(f);
  b += 0x7FFFu + ((b >> 16) & 1u);
  return (unsigned short)(b >> 16);
}

__device__ __forceinline__ float gelu_exact(float v) {
  return 0.5f * v * (1.0f + erff(v * 0.70710678118654752440f));
}

__device__ __forceinline__ void cvt8(const float* __restrict__ src, unsigned short* __restrict__ dst,
                                     size_t i) {
  const f32x4* p = (const f32x4*)src;
  f32x4 a = p[2 * i];
  f32x4 b = p[2 * i + 1];
  union { bf16x8 v; unsigned short u[8]; } o;
  o.u[0] = f2bf(a.x); o.u[1] = f2bf(a.y); o.u[2] = f2bf(a.z); o.u[3] = f2bf(a.w);
  o.u[4] = f2bf(b.x); o.u[5] = f2bf(b.y); o.u[6] = f2bf(b.z); o.u[7] = f2bf(b.w);
  ((bf16x8*)dst)[i] = o.v;
}

// ---- standalone grid-stride cvt (fallback path) ----
__global__ void cvt_kernel(const float* __restrict__ x, unsigned short* __restrict__ xb, size_t n) {
  size_t tid = (size_t)blockIdx.x * blockDim.x + threadIdx.x;
  size_t stride = (size_t)gridDim.x * blockDim.x;
  for (size_t u = tid; u < n; u += stride) cvt8(x, xb, u);
}

// ---- fused: router (first 128 blocks) | grid-stride cvt of x then up ----
__global__ void fused_pre_kernel(const float* __restrict__ x, unsigned short* __restrict__ xb,
                                 const float* __restrict__ up, unsigned short* __restrict__ upb,
                                 const float* __restrict__ rw, const float* __restrict__ rb,
                                 int* __restrict__ counts_pad, int* __restrict__ tlist,
                                 float* __restrict__ wlist) {
  const int bid = blockIdx.x;
  if (bid >= ROUT_BLOCKS) {
    // grid-stride cvt: x (NXU units) then up (NWU units); ~10 independent iters/thread
    size_t tid = (size_t)(bid - ROUT_BLOCKS) * 256 + threadIdx.x;
    for (size_t u = tid; u < NXU; u += CVT_GS_THREADS) cvt8(x, xb, u);
    for (size_t u = tid; u < NWU; u += CVT_GS_THREADS) cvt8(up, upb, u);
    return;
  }
  // ---- router: 64 tokens per block, f32x4-vectorized x reads ----
  const int rblk = bid;
  __shared__ int hcnt[NE], hbase[NE];
  __shared__ int tE1[64], tE2[64], tR1[64], tR2[64];
  __shared__ float tW1[64], tW2[64];
  if (threadIdx.x < NE) hcnt[threadIdx.x] = 0;
  __syncthreads();
  const int wv = threadIdx.x >> 6, lane = threadIdx.x & 63;
#pragma unroll 1
  for (int it = 0; it < 16; ++it) {
    const int lt = wv * 16 + it;
    const int t = rblk * 64 + lt;
    const float* xr = x + (size_t)t * DM;
    float acc[NE];
#pragma unroll
    for (int e = 0; e < NE; ++e) acc[e] = 0.0f;
#pragma unroll
    for (int i = 0; i < 4; ++i) {
      int d0 = lane * 4 + i * 256;
      f32x4 xv = *(const f32x4*)(xr + d0);
#pragma unroll
      for (int j = 0; j < 4; ++j) {
        const float* wr = rw + (size_t)(d0 + j) * NE;
#pragma unroll
        for (int e = 0; e < NE; ++e) acc[e] = fmaf(xv[j], wr[e], acc[e]);
      }
    }
#pragma unroll
    for (int off = 32; off; off >>= 1) {
#pragma unroll
      for (int e = 0; e < NE; ++e) acc[e] += __shfl_xor(acc[e], off);
    }
    if (lane == 0) {
      float m = -1e30f;
#pragma unroll
      for (int e = 0; e < NE; ++e) { acc[e] += rb[e]; m = fmaxf(m, acc[e]); }
      float p[NE]; float s = 0.0f;
#pragma unroll
      for (int e = 0; e < NE; ++e) { p[e] = expf(acc[e] - m); s += p[e]; }
      int e1 = 0; float p1 = p[0];
#pragma unroll
      for (int e = 1; e < NE; ++e) if (p[e] > p1) { p1 = p[e]; e1 = e; }
      int e2 = -1; float p2 = -1e30f;
#pragma unroll
      for (int e = 0; e < NE; ++e) if (e != e1 && p[e] > p2) { p2 = p[e]; e2 = e; }
      float inv = 1.0f / s;
      int r1 = atomicAdd(&hcnt[e1], 1);
      int r2 = atomicAdd(&hcnt[e2], 1);
      tE1[lt] = e1; tR1[lt] = r1; tW1[lt] = p1 * inv;
      tE2[lt] = e2; tR2[lt] = r2; tW2[lt] = p2 * inv;
    }
  }
  __syncthreads();
  if (threadIdx.x < NE)
    hbase[threadIdx.x] = atomicAdd(&counts_pad[threadIdx.x * 16], hcnt[threadIdx.x]);
  __syncthreads();
  if (threadIdx.x < 64) {
    int lt = threadIdx.x;
    int t = rblk * 64 + lt;
    int e = tE1[lt]; int pos = hbase[e] + tR1[lt];
    tlist[e * T_TOK + pos] = t; wlist[e * T_TOK + pos] = tW1[lt];
    e = tE2[lt]; pos = hbase[e] + tR2[lt];
    tlist[e * T_TOK + pos] = t; wlist[e * T_TOK + pos] = tW2[lt];
  }
}

// ---- prefix + per-XCD worklists (parallel fill); compacts padded counts ----
// pack: e<<24 | rt<<16 | kh<<8 | ct ; -1 = no work
__global__ void prefix_kernel(const int* __restrict__ counts_pad, int* __restrict__ cntc,
                              int* __restrict__ offs,
                              int* __restrict__ wl_up, int* __restrict__ wl_dn) {
  __shared__ int te[144], tr[144], sn;
  if (threadIdx.x == 0) {
    int s = 0, n = 0;
    for (int e = 0; e < NE; ++e) {
      int c = counts_pad[e * 16];
      cntc[e] = c;
      offs[e] = s; s += c;
      int ntile = (c + 127) / 128;
      for (int r = 0; r < ntile; ++r) { te[n] = e; tr[n] = r; ++n; }
    }
    sn = n;
  }
  __syncthreads();
  const int n = sn;
  for (int idx = threadIdx.x; idx < 8 * PERX_UP; idx += blockDim.x) {
    int k = idx / PERX_UP, i = idx % PERX_UP;
    int g0 = (n * k) / 8, g1 = (n * (k + 1)) / 8, gc = g1 - g0;
    int v = -1;
    if (gc > 0 && i < 32 * gc) {
      // super-tiled: gsb blocks of up to 8 g-rows; within each, 4 csb runs of 8 ct
      int rem = i, gsb = 0, gs = (gc < 8 ? gc : 8);
      while (rem >= 32 * gs) {
        rem -= 32 * gs; ++gsb;
        int left = gc - gsb * 8; gs = (left < 8 ? left : 8);
      }
      int csb = rem / (8 * gs);
      int r2 = rem % (8 * gs);
      int gi = r2 / 8, ci = r2 & 7;
      int ct = csb * 8 + ci;
      int g = g0 + gsb * 8 + gi;
      v = (te[g] << 24) | (tr[g] << 16) | ct;
    }
    wl_up[idx] = v;
  }
  for (int idx = threadIdx.x; idx < 8 * PERX_DN; idx += blockDim.x) {
    int k = idx / PERX_DN, i = idx % PERX_DN;
    int g0 = (n * k) / 8, g1 = (n * (k + 1)) / 8, gc = g1 - g0;
    int v = -1;
    if (gc > 0 && i < 16 * gc) {          // kh-outer, ct-mid, g-inner
      int kh = i / (8 * gc);
      int rem = i % (8 * gc);
      int ct = rem / gc, g = g0 + rem % gc;
      v = (te[g] << 24) | (tr[g] << 16) | (kh << 8) | ct;
    }
    wl_dn[idx] = v;
  }
}

#define GL2LDS16(g, l) \
  __builtin_amdgcn_global_load_lds((const __attribute__((address_space(1))) unsigned int*)(g), \
                                   (__attribute__((address_space(3))) unsigned int*)(l), 16, 0, 0)

#define VMCNT4   asm volatile("s_waitcnt vmcnt(4)" ::: "memory")
#define VMCNT0   asm volatile("s_waitcnt vmcnt(0)" ::: "memory")
#define LGKM0    asm volatile("s_waitcnt lgkmcnt(0)" ::: "memory")
#define BARRIER() do { asm volatile("" ::: "memory"); __builtin_amdgcn_s_barrier(); asm volatile("" ::: "memory"); } while (0)

// per-wave staging: 4 gl2lds (2 A + 2 B) into buffer bi; tile t covers k0 = t*32
#define STAGE(bi, t) do { \
  const int k_ = (t) * 32; \
  GL2LDS16(asrc0 + k_, smem + (bi) * 4096 + wv * 512); \
  GL2LDS16(asrc1 + k_, smem + (bi) * 4096 + wv * 512 + 2048); \
  GL2LDS16(bsrc0 + k_, smem + 8192 + (bi) * 4096 + wv * 512); \
  GL2LDS16(bsrc1 + k_, smem + 8192 + (bi) * 4096 + wv * 512 + 2048); \
} while (0)

// swizzled reads + 16 MFMA on buffer bi
#define COMPUTE(bi) do { \
  const unsigned short* sA_ = smem + (bi) * 4096; \
  const unsigned short* sB_ = smem + 8192 + (bi) * 4096; \
  bf16x8 af_[4], bf_[4]; \
  _Pragma("unroll") \
  for (int m_ = 0; m_ < 4; ++m_) af_[m_] = *(const bf16x8*)(sA_ + (wr + m_ * 16 + lr) * 32 + kx); \
  _Pragma("unroll") \
  for (int n_ = 0; n_ < 4; ++n_) bf_[n_] = *(const bf16x8*)(sB_ + (wc + n_ * 16 + lr) * 32 + kx); \
  _Pragma("unroll") \
  for (int m_ = 0; m_ < 4; ++m_) \
    _Pragma("unroll") \
    for (int n_ = 0; n_ < 4; ++n_) \
      acc[m_][n_] = __builtin_amdgcn_mfma_f32_16x16x32_bf16(af_[m_], bf_[n_], acc[m_][n_], 0, 0, 0); \
} while (0)

// depth-2 pipelined K-loop: tile t's loads issued 2 steps ahead -> no exposed latency
#define KLOOP(NT) do { \
  STAGE(0, 0); \
  STAGE(1, 1); \
  for (int t = 0; t < (NT); ++t) { \
    const int b_ = t & 1; \
    if (t + 1 < (NT)) { VMCNT4; } else { VMCNT0; } \
    BARRIER(); \
    COMPUTE(b_); \
    if (t + 2 < (NT)) { \
      LGKM0; \
      BARRIER(); \
      STAGE(b_, t + 2); \
    } \
  } \
} while (0)

// ---- GEMM1: h = gelu(x[tok] @ up[e]^T), 128x128/BK=32, depth-2; trailing grid-stride cvt dn ----
__global__ __launch_bounds__(256, 4) void gemm_up_kernel(
    const unsigned short* __restrict__ xb, const unsigned short* __restrict__ wb,
    const int* __restrict__ cntc, const int* __restrict__ offs,
    const int* __restrict__ wl, const int* __restrict__ tlist,
    unsigned short* __restrict__ h,
    const float* __restrict__ dn_f32, unsigned short* __restrict__ dn_bf16) {
  if ((int)blockIdx.x >= GEMM_UP_BLOCKS) {
    size_t tid = (size_t)(blockIdx.x - GEMM_UP_BLOCKS) * 256 + threadIdx.x;
    for (size_t u = tid; u < NWU; u += CVT_GS_THREADS) cvt8(dn_f32, dn_bf16, u);
    return;
  }
  const int xcd = blockIdx.x & 7, slot = blockIdx.x >> 3;
  const int item = wl[xcd * PERX_UP + slot];
  if (item < 0) return;
  const int e = (item >> 24) & 7, rt = (item >> 16) & 0xFF, ct = item & 0xFF;
  const int cnt = cntc[e];

  __shared__ unsigned short smem[16384];   // 32 KB: sA[2] + sB[2]; sH bounce reuses

  const int tid = threadIdx.x;
  const int wv = tid >> 6, ln = tid & 63;
  const int swz = (tid & 3) ^ ((tid >> 3) & 3);

  const int arow = wv * 16 + (ln >> 2);
  int r0 = rt * 128 + arow;
  int r1 = r0 + 64;
  const int tok0 = tlist[e * T_TOK + (r0 < cnt ? r0 : cnt - 1)];
  const int tok1 = tlist[e * T_TOK + (r1 < cnt ? r1 : cnt - 1)];
  const unsigned short* asrc0 = xb + (size_t)tok0 * DM + swz * 8;
  const unsigned short* asrc1 = xb + (size_t)tok1 * DM + swz * 8;

  const unsigned short* bsrc0 =
      wb + (size_t)e * DFF * DM + (size_t)(ct * 128 + arow) * DM + swz * 8;
  const unsigned short* bsrc1 = bsrc0 + (size_t)64 * DM;

  const int wr = (wv >> 1) * 64, wc = (wv & 1) * 64;
  const int lr = ln & 15;
  const int kx = (((ln >> 4) ^ ((lr >> 1) & 3))) * 8;

  f32x4 acc[4][4] = {};

  KLOOP(DM / 32);   // 32 steps

  BARRIER();        // all waves done with sA/sB before reuse as sH

  unsigned short* sH = smem;               // [128][128] = 32 KB
#pragma unroll
  for (int m = 0; m < 4; ++m) {
    int rloc = wr + m * 16 + (ln >> 4) * 4;
#pragma unroll
    for (int j = 0; j < 4; ++j) {
      int row = rloc + j;
#pragma unroll
      for (int n = 0; n < 4; ++n) {
        int col = wc + n * 16 + lr;
        int sl = ((col >> 3) ^ (row & 7)) * 8 + (col & 7);
        sH[row * 128 + sl] = f2bf(gelu_exact(acc[m][n][j]));
      }
    }
  }
  __syncthreads();
  const size_t hbase = (size_t)offs[e];
#pragma unroll
  for (int it = 0; it < 8; ++it) {
    int idx = it * 256 + tid;
    int row = idx >> 4, c8 = idx & 15;
    if (rt * 128 + row < cnt) {
      unsigned short* hp = h + (hbase + rt * 128 + row) * (size_t)DFF + ct * 128 + c8 * 8;
      *(bf16x8*)hp = *(const bf16x8*)&sH[row * 128 + (c8 ^ (row & 7)) * 8];
    }
  }
}

// ---- GEMM2: out[tok] += w * (h @ down[e]^T), 128x128/BK=32, K-split-2, depth-2 ----
__global__ __launch_bounds__(256, 4) void gemm_down_kernel(
    const unsigned short* __restrict__ h, const unsigned short* __restrict__ wb,
    const int* __restrict__ cntc, const int* __restrict__ offs,
    const int* __restrict__ wl, const int* __restrict__ tlist,
    const float* __restrict__ wlist, float* __restrict__ out) {
  const int xcd = blockIdx.x & 7, slot = blockIdx.x >> 3;
  const int item = wl[xcd * PERX_DN + slot];
  if (item < 0) return;
  const int e = (item >> 24) & 7, rt = (item >> 16) & 0xFF;
  const int kh = (item >> 8) & 1, ct = item & 0xFF;
  const int cnt = cntc[e];

  __shared__ unsigned short smem[16384];   // 32 KB

  const int tid = threadIdx.x;
  const int wv = tid >> 6, ln = tid & 63;
  const int swz = (tid & 3) ^ ((tid >> 3) & 3);
  const size_t hbase = (size_t)offs[e];
  const int kbase = kh * (DFF / 2);

  const int arow = wv * 16 + (ln >> 2);
  int r0 = rt * 128 + arow;
  int r1 = r0 + 64;
  const unsigned short* asrc0 =
      h + (hbase + (r0 < cnt ? r0 : cnt - 1)) * (size_t)DFF + kbase + swz * 8;
  const unsigned short* asrc1 =
      h + (hbase + (r1 < cnt ? r1 : cnt - 1)) * (size_t)DFF + kbase + swz * 8;

  const unsigned short* bsrc0 =
      wb + (size_t)e * DM * DFF + (size_t)(ct * 128 + arow) * DFF + kbase + swz * 8;
  const unsigned short* bsrc1 = bsrc0 + (size_t)64 * DFF;

  const int wr = (wv >> 1) * 64, wc = (wv & 1) * 64;
  const int lr = ln & 15;
  const int kx = (((ln >> 4) ^ ((lr >> 1) & 3))) * 8;

  f32x4 acc[4][4] = {};

  KLOOP(DFF / 2 / 32);   // 64 steps

#pragma unroll
  for (int m = 0; m < 4; ++m) {
    int rloc = wr + m * 16 + (ln >> 4) * 4;
#pragma unroll
    for (int j = 0; j < 4; ++j) {
      int row = rt * 128 + rloc + j;
      if (row < cnt) {
        int tok = tlist[e * T_TOK + row];
        float w = wlist[e * T_TOK + row];
        float* op = out + (size_t)tok * DM + ct * 128 + wc + lr;
#pragma unroll
        for (int n = 0; n < 4; ++n) atomicAdd(op + n * 16, w * acc[m][n][j]);
      }
    }
  }
}

extern "C" void kernel_launch(void* const* d_in, const int* in_sizes, int n_in,
                              void* d_out, int out_size, void* d_ws, size_t ws_size,
                              hipStream_t stream) {
  const float* x  = (const float*)d_in[0];
  const float* rw = (const float*)d_in[1];
  const float* rb = (const float*)d_in[2];
  const float* up = (const float*)d_in[3];
  const float* dn = (const float*)d_in[4];
  float* out = (float*)d_out;
  char* ws = (char*)d_ws;

  int*   counts_pad = (int*)(ws + 0);                       // 8 counters x 64B
  int*   cntc   = (int*)(ws + 1024);
  int*   offs   = (int*)(ws + 2048);
  int*   wl_up  = (int*)(ws + 4096);                        // 8*576 ints
  int*   wl_dn  = (int*)(ws + 24576);                       // 8*288 ints
  int*   tlist  = (int*)(ws + 65536);                       // 256 KB
  float* wlist  = (float*)(ws + 65536 + 262144);            // 256 KB
  unsigned short* xb    = (unsigned short*)(ws + 589824);   // 16 MB
  unsigned short* h     = (unsigned short*)(ws + 17367040); // 128 MB
  unsigned short* wbufA = (unsigned short*)(ws + 151584768);// 64 MB (up weights)
  unsigned short* wbufB = (unsigned short*)(ws + 218693632);// 64 MB (dn weights, big-ws only)
  const bool big_ws = (ws_size >= (size_t)218693632 + 67108864);

  hipMemsetAsync(counts_pad, 0, 512, stream);
  hipMemsetAsync(d_out, 0, (size_t)T_TOK * DM * sizeof(float), stream);

  // fused: router (128 blocks) + grid-stride cvt of x and up (2048 blocks)
  fused_pre_kernel<<<dim3(ROUT_BLOCKS + CVT_GS_BLOCKS), 256, 0, stream>>>(
      x, xb, up, wbufA, rw, rb, counts_pad, tlist, wlist);
  prefix_kernel<<<dim3(1), 256, 0, stream>>>(counts_pad, cntc, offs, wl_up, wl_dn);

  if (big_ws) {
    // gemm_up + 2048 trailing grid-stride cvt-dn blocks (overlapped)
    gemm_up_kernel<<<dim3(GEMM_UP_BLOCKS + CVT_GS_BLOCKS), 256, 0, stream>>>(
        xb, wbufA, cntc, offs, wl_up, tlist, h, dn, wbufB);
    gemm_down_kernel<<<dim3(8 * PERX_DN), 256, 0, stream>>>(
        h, wbufB, cntc, offs, wl_dn, tlist, wlist, out);
  } else {
    gemm_up_kernel<<<dim3(GEMM_UP_BLOCKS), 256, 0, stream>>>(
        xb, wbufA, cntc, offs, wl_up, tlist, h, dn, wbufA);
    cvt_kernel<<<dim3(CVT_GS_BLOCKS), 256, 0, stream>>>(dn, (unsigned short*)wbufA, NWU);
    gemm_down_kernel<<<dim3(8 * PERX_DN), 256, 0, stream>>>(
        h, wbufA, cntc, offs, wl_dn, tlist, wlist, out);
  }
}